// Round 24
// baseline (204.687 us; speedup 1.0000x reference)
//
#include <hip/hip_runtime.h>

namespace {
constexpr int NN  = 100000;   // nodes
constexpr int NE  = 1000000;  // edges
constexpr int INF = 256;
constexpr int HF  = 64;
constexpr int OF  = 16;
constexpr int SCAN_CHUNK = 1024;
constexpr int NBLK = (NN + SCAN_CHUNK - 1) / SCAN_CHUNK; // 98
constexpr int NSEG = 8;
constexpr int SEGW = (NN + NSEG - 1) / NSEG;             // 12500
constexpr int CNTW = 100096;
constexpr int ZBLK = (CNTW / 4 + 255) / 256;             // 98
constexpr int GB   = (NN + 31) / 32;                     // 3125 gemm1 blocks (32 rows each)
constexpr int ECHUNK = 2048;
constexpr int EGRP = (NE + ECHUNK - 1) / ECHUNK;         // 489
constexpr int SB   = EGRP * NSEG;                        // 3912 hist blocks
constexpr int SCB  = EGRP;                               // 489 scatter blocks
}

typedef __attribute__((ext_vector_type(8))) short     sh8;
typedef __attribute__((ext_vector_type(4))) float     f32x4;
typedef __attribute__((ext_vector_type(8))) unsigned short us8;

__device__ __forceinline__ unsigned short f2bf(float f) {
    unsigned int u = __builtin_bit_cast(unsigned int, f);
    u += 0x7FFFu + ((u >> 16) & 1u);       // round-to-nearest-even
    return (unsigned short)(u >> 16);
}
__device__ __forceinline__ float bf2f(unsigned short s) {
    return __builtin_bit_cast(float, (unsigned int)s << 16);
}

// ---- pre: zero cnt + W1 -> bf16 transposed, one launch ---------------------
__global__ void k_pre(int* __restrict__ cnt, const float* __restrict__ W1,
                      unsigned short* __restrict__ wt_g) {
    int b = blockIdx.x, t = threadIdx.x;
    if (b < ZBLK) {
        int i = (b * 256 + t) * 4;
        if (i < CNTW) *(int4*)(cnt + i) = (int4){0, 0, 0, 0};
    } else {
        int idx = (b - ZBLK) * 256 + t;       // 16384 tasks
        int c = idx >> 8, k = idx & 255;
        wt_g[idx] = f2bf(W1[(size_t)k * HF + c]);
    }
}

// ---- degree histogram + RANK capture: 8 edges/thread, XCD-pinned segments --
__global__ __launch_bounds__(256) void k_hist(const int* __restrict__ dst,
                                              int* __restrict__ cnt,
                                              int* __restrict__ rank) {
    int b   = blockIdx.x;
    int seg = b & (NSEG - 1);
    int grp = b >> 3;
    int e0  = grp * ECHUNK + threadIdx.x;
    int d[8];
    #pragma unroll
    for (int i = 0; i < 8; ++i) {
        int e = e0 + i * 256;
        d[i] = (e < NE) ? dst[e] : -1;
    }
    #pragma unroll
    for (int i = 0; i < 8; ++i) {
        if ((unsigned)d[i] / (unsigned)SEGW == (unsigned)seg)
            rank[e0 + i * 256] = atomicAdd(&cnt[d[i]], 1);
    }
}

// ---- block-reduce of cnt -> bsum, fused dinv = rsqrt(cnt+1) ----------------
__global__ __launch_bounds__(256) void k_reduce(const int* __restrict__ cnt,
                                                int* __restrict__ bsum,
                                                float* __restrict__ dinv) {
    int t = threadIdx.x;
    int i0 = blockIdx.x * SCAN_CHUNK + t * 4;
    int s = 0;
    float dv[4] = {0.f, 0.f, 0.f, 0.f};
    #pragma unroll
    for (int q = 0; q < 4; ++q) {
        if (i0 + q < NN) {
            int c = cnt[i0 + q];
            s += c;
            dv[q] = rsqrtf((float)(c + 1));
        }
    }
    if (i0 + 3 < NN) *(float4*)(dinv + i0) = (float4){dv[0], dv[1], dv[2], dv[3]};
    else { for (int q = 0; q < 4; ++q) if (i0 + q < NN) dinv[i0 + q] = dv[q]; }
    #pragma unroll
    for (int off = 32; off > 0; off >>= 1) s += __shfl_down(s, off);
    __shared__ int wsum[4];
    int lane = t & 63, wid = t >> 6;
    if (lane == 0) wsum[wid] = s;
    __syncthreads();
    if (t == 0) bsum[blockIdx.x] = wsum[0] + wsum[1] + wsum[2] + wsum[3];
}

// ---- scan: each block derives its own prefix from bsum ---------------------
__global__ __launch_bounds__(256) void k_scan(const int* __restrict__ cnt,
                                              const int* __restrict__ bsum,
                                              int* __restrict__ rowptr) {
    int t = threadIdx.x;
    int b = blockIdx.x;
    int lane = t & 63, wid = t >> 6;

    int p = 0;
    if (lane < b) p += bsum[lane];
    if (64 + lane < b) p += bsum[64 + lane];
    #pragma unroll
    for (int off = 32; off > 0; off >>= 1) p += __shfl_down(p, off);
    int blockBase = __shfl(p, 0);

    int i0 = b * SCAN_CHUNK + t * 4;
    int v0 = 0, v1 = 0, v2 = 0, v3 = 0;
    if (i0 + 0 < NN) v0 = cnt[i0 + 0];
    if (i0 + 1 < NN) v1 = cnt[i0 + 1];
    if (i0 + 2 < NN) v2 = cnt[i0 + 2];
    if (i0 + 3 < NN) v3 = cnt[i0 + 3];
    int tsum = v0 + v1 + v2 + v3;
    int incl = tsum;
    #pragma unroll
    for (int off = 1; off < 64; off <<= 1) {
        int n = __shfl_up(incl, off);
        if (lane >= off) incl += n;
    }
    __shared__ int wsum[4];
    if (lane == 63) wsum[wid] = incl;
    __syncthreads();
    int woff = 0;
    for (int w = 0; w < wid; ++w) woff += wsum[w];
    int excl = woff + (incl - tsum) + blockBase;
    int e0 = excl, e1 = e0 + v0, e2 = e1 + v1, e3 = e2 + v2;
    if (i0 + 0 < NN) rowptr[i0 + 0] = e0;
    if (i0 + 1 < NN) rowptr[i0 + 1] = e1;
    if (i0 + 2 < NN) rowptr[i0 + 2] = e2;
    if (i0 + 3 < NN) rowptr[i0 + 3] = e3;
    if (i0 + 3 == NN - 1) rowptr[NN] = e3 + v3;
}

// ---- FUSED: gemm1 32-row blocks (0..GB-1) || atomic-free scatter (GB..) ----
// R23 lesson: old 128-row gemm (782 blocks @ 8/CU) concentrated the whole
// 102MB x-stream on ~98 CUs (~1MB/CU -> ~42us at the per-CU port rate).
// 32-row blocks (3125) spread x across all 256 CUs (~400KB/CU). Waves split
// the N dim: wave w computes cols w*16..w*16+15 (16 MFMAs/wave); the 32KB
// row-tile is L1-absorbed across the 4 waves. Barrier-free; B from L1-resident
// wt_g; scatter path = R21/R22 atomic-free rank/rowptr form.
__global__ __launch_bounds__(256, 8) void k_gs(const float* __restrict__ x,
                                               const unsigned short* __restrict__ wt_g,
                                               unsigned short* __restrict__ h1,
                                               const int* __restrict__ src,
                                               const int* __restrict__ dst,
                                               const int* __restrict__ rank,
                                               const int* __restrict__ rowptr,
                                               int* __restrict__ eidx) {
    int b = blockIdx.x;
    int t = threadIdx.x;

    if (b >= GB) {
        // ---- atomic-free scatter path ----
        int sb = b - GB;
        int e0 = sb * ECHUNK + t;
        #pragma unroll
        for (int i = 0; i < 8; ++i) {
            int e = e0 + i * 256;
            if (e < NE) {
                int d = dst[e];
                eidx[rowptr[d] + rank[e]] = src[e];
            }
        }
        return;
    }

    // ---- gemm1 path: 32 rows, wave w -> cols w*16..w*16+15 ----
    int w = t >> 6, l = t & 63;
    int row0 = b * 32;
    int m = l & 15;
    int g = l >> 4;
    int gr0 = row0 + m;      if (gr0 > NN - 1) gr0 = NN - 1;
    int gr1 = row0 + 16 + m; if (gr1 > NN - 1) gr1 = NN - 1;
    const float* p0 = x + (size_t)gr0 * INF + g * 8;
    const float* p1 = x + (size_t)gr1 * INF + g * 8;
    const unsigned short* wb = wt_g + (size_t)(w * 16 + m) * 256 + g * 8;

    f32x4 acc0 = (f32x4){0.f, 0.f, 0.f, 0.f};
    f32x4 acc1 = (f32x4){0.f, 0.f, 0.f, 0.f};

    #pragma unroll
    for (int kb = 0; kb < INF; kb += 32) {
        float4 u0 = *(const float4*)(p0 + kb);
        float4 u1 = *(const float4*)(p0 + kb + 4);
        float4 u2 = *(const float4*)(p1 + kb);
        float4 u3 = *(const float4*)(p1 + kb + 4);
        sh8 bb = *(const sh8*)(wb + kb);
        us8 a0u = { f2bf(u0.x), f2bf(u0.y), f2bf(u0.z), f2bf(u0.w),
                    f2bf(u1.x), f2bf(u1.y), f2bf(u1.z), f2bf(u1.w) };
        us8 a1u = { f2bf(u2.x), f2bf(u2.y), f2bf(u2.z), f2bf(u2.w),
                    f2bf(u3.x), f2bf(u3.y), f2bf(u3.z), f2bf(u3.w) };
        sh8 a0 = __builtin_bit_cast(sh8, a0u);
        sh8 a1 = __builtin_bit_cast(sh8, a1u);
        acc0 = __builtin_amdgcn_mfma_f32_16x16x32_bf16(a0, bb, acc0, 0, 0, 0);
        acc1 = __builtin_amdgcn_mfma_f32_16x16x32_bf16(a1, bb, acc1, 0, 0, 0);
    }

    // epilogue: D row = g*4+r, col = l&15 -> h1[row0 + mt*16 + g*4 + r][w*16 + col]
    #pragma unroll
    for (int r = 0; r < 4; ++r) {
        int gr = row0 + g * 4 + r;
        if (gr < NN) h1[(size_t)gr * HF + w * 16 + m] = f2bf(acc0[r]);
    }
    #pragma unroll
    for (int r = 0; r < 4; ++r) {
        int gr = row0 + 16 + g * 4 + r;
        if (gr < NN) h1[(size_t)gr * HF + w * 16 + m] = f2bf(acc1[r]);
    }
}

// ---- Gather layer 1: 8 nodes/wave, 8 lanes/node, lane owns 8 feats ---------
__global__ __launch_bounds__(256) void k_gather1(const int* __restrict__ rowptr,
                                                 const int* __restrict__ eidx,
                                                 const float* __restrict__ dinv,
                                                 const unsigned short* __restrict__ h1,
                                                 const float* __restrict__ b1,
                                                 const float* __restrict__ W2,
                                                 unsigned short* __restrict__ h2) {
    __shared__ float w2L[HF * OF];     // 4KB, [k][j]
    __shared__ float hrL[32][HF + 4];  // 8.5KB, stride 68 (bank-spread)
    int t = threadIdx.x;
    *(float4*)(w2L + t * 4) = *(const float4*)(W2 + t * 4);

    int nodeL = t >> 3;
    int fg    = t & 7;
    int v     = blockIdx.x * 32 + nodeL;   // NN = 3125*32 exact
    int beg = rowptr[v], end = rowptr[v + 1];

    float acc[8] = {};
    int   s_n = 0;  float w_n = 0.f;  us8 h_n = {};
    if (beg < end) {
        s_n = eidx[beg];
        w_n = dinv[s_n];
        h_n = *(const us8*)(h1 + (size_t)s_n * HF + fg * 8);
    }
    for (int i = beg; i < end; ++i) {
        float w_c = w_n;  us8 h_c = h_n;
        if (i + 1 < end) {
            s_n = eidx[i + 1];
            w_n = dinv[s_n];
            h_n = *(const us8*)(h1 + (size_t)s_n * HF + fg * 8);
        }
        #pragma unroll
        for (int q = 0; q < 8; ++q) acc[q] += w_c * bf2f(h_c[q]);
    }

    {
        float dv = dinv[v], sl = dv * dv;
        us8 hv = *(const us8*)(h1 + (size_t)v * HF + fg * 8);
        #pragma unroll
        for (int q = 0; q < 8; ++q) {
            float val = dv * acc[q] + sl * bf2f(hv[q]) + b1[fg * 8 + q];
            hrL[nodeL][fg * 8 + q] = val > 0.f ? val : 0.f;
        }
    }
    __syncthreads();

    #pragma unroll
    for (int T = t; T < 512; T += 256) {
        int n = T >> 4, j = T & 15;
        const float* hr = hrL[n];
        float p = 0.f;
        #pragma unroll
        for (int k = 0; k < HF; ++k) p += hr[k] * w2L[k * OF + j];
        h2[(size_t)(blockIdx.x * 32 + n) * OF + j] = f2bf(p);
    }
}

// ---- Gather layer 2: 16 nodes/block, 16 lanes/node, lane owns 1 out-feat ---
__global__ __launch_bounds__(256) void k_gather2(const int* __restrict__ rowptr,
                                                 const int* __restrict__ eidx,
                                                 const float* __restrict__ dinv,
                                                 const unsigned short* __restrict__ h2,
                                                 const float* __restrict__ b2,
                                                 float* __restrict__ out) {
    int t     = threadIdx.x;
    int nodeL = t >> 4;
    int j     = t & 15;
    int v     = blockIdx.x * 16 + nodeL;   // NN = 6250*16 exact
    int beg = rowptr[v], end = rowptr[v + 1];

    float acc = 0.f;
    int   s_n = 0;  float w_n = 0.f;  unsigned short h_n = 0;
    if (beg < end) {
        s_n = eidx[beg];
        w_n = dinv[s_n];
        h_n = h2[(size_t)s_n * OF + j];
    }
    for (int i = beg; i < end; ++i) {
        float w_c = w_n;  unsigned short h_c = h_n;
        if (i + 1 < end) {
            s_n = eidx[i + 1];
            w_n = dinv[s_n];
            h_n = h2[(size_t)s_n * OF + j];
        }
        acc += w_c * bf2f(h_c);
    }
    float dv = dinv[v];
    out[(size_t)v * OF + j] = dv * acc + dv * dv * bf2f(h2[(size_t)v * OF + j]) + b2[j];
}

extern "C" void kernel_launch(void* const* d_in, const int* in_sizes, int n_in,
                              void* d_out, int out_size, void* d_ws, size_t ws_size,
                              hipStream_t stream) {
    const float* x   = (const float*)d_in[0];
    const int*   ei  = (const int*)d_in[1];
    const int*   src = ei;
    const int*   dst = ei + NE;
    const float* W1  = (const float*)d_in[2];
    const float* b1  = (const float*)d_in[3];
    const float* W2  = (const float*)d_in[4];
    const float* b2  = (const float*)d_in[5];
    float* out = (float*)d_out;

    // workspace layout (4B units)
    float* dinv   = (float*)d_ws;                          // [CNTW]
    unsigned short* h1b = (unsigned short*)(dinv + CNTW);  // [NN*64] bf16
    unsigned short* h2b = (unsigned short*)(h1b + (size_t)NN * HF);  // [NN*16] bf16
    int*   cnt    = (int*)(h2b + (size_t)NN * OF + (size_t)NN * OF); // [CNTW]
    int*   rowptr = cnt + CNTW;                            // [100352]
    int*   rank   = rowptr + 100352;                       // [NE]
    int*   eidx   = rank + NE;                             // [NE]
    int*   bsum   = eidx + NE;                             // [128]
    unsigned short* wt_g = (unsigned short*)(bsum + 128);  // [64*256] bf16

    // CSR build + norms + W pre-transpose
    k_pre<<<ZBLK + 64, 256, 0, stream>>>(cnt, W1, wt_g);
    k_hist<<<SB, 256, 0, stream>>>(dst, cnt, rank);
    k_reduce<<<NBLK, 256, 0, stream>>>(cnt, bsum, dinv);
    k_scan<<<NBLK, 256, 0, stream>>>(cnt, bsum, rowptr);

    // gemm1 (32-row blocks, all CUs) || atomic-free scatter in one launch
    k_gs<<<GB + SCB, 256, 0, stream>>>(x, wt_g, h1b, src, dst, rank, rowptr, eidx);

    // layer 1 aggregation (+ fused layer-2 GEMM)
    k_gather1<<<NN / 32, 256, 0, stream>>>(rowptr, eidx, dinv, h1b, b1, W2, h2b);

    // layer 2 aggregation
    k_gather2<<<NN / 16, 256, 0, stream>>>(rowptr, eidx, dinv, h2b, b2, out);
}

// Round 25
// 167.225 us; speedup vs baseline: 1.2240x; 1.2240x over previous
//
#include <hip/hip_runtime.h>

namespace {
constexpr int NN  = 100000;   // nodes
constexpr int NE  = 1000000;  // edges
constexpr int INF = 256;
constexpr int HF  = 64;
constexpr int OF  = 16;
constexpr int SCAN_CHUNK = 1024;
constexpr int NBLK = (NN + SCAN_CHUNK - 1) / SCAN_CHUNK; // 98
constexpr int NSEG = 8;
constexpr int SEGW = (NN + NSEG - 1) / NSEG;             // 12500
constexpr int CNTW = 100096;
constexpr int ZBLK = (CNTW / 4 + 255) / 256;             // 98
constexpr int GB   = (NN + 127) / 128;                   // 782 gemm1 blocks
constexpr int ECHUNK = 2048;
constexpr int EGRP = (NE + ECHUNK - 1) / ECHUNK;         // 489
constexpr int SB   = EGRP * NSEG;                        // 3912 hist blocks
constexpr int SCB  = EGRP;                               // 489 scatter blocks
}

typedef __attribute__((ext_vector_type(8))) short     sh8;
typedef __attribute__((ext_vector_type(4))) float     f32x4;
typedef __attribute__((ext_vector_type(8))) unsigned short us8;

__device__ __forceinline__ unsigned short f2bf(float f) {
    unsigned int u = __builtin_bit_cast(unsigned int, f);
    u += 0x7FFFu + ((u >> 16) & 1u);       // round-to-nearest-even
    return (unsigned short)(u >> 16);
}
__device__ __forceinline__ float bf2f(unsigned short s) {
    return __builtin_bit_cast(float, (unsigned int)s << 16);
}

__device__ __forceinline__ void gload_lds16(const void* g, void* l) {
    __builtin_amdgcn_global_load_lds(
        (const __attribute__((address_space(1))) void*)g,
        (__attribute__((address_space(3))) void*)l, 16, 0, 0);
}

// ---- pre: zero cnt + W1 -> bf16 transposed, one launch ---------------------
__global__ void k_pre(int* __restrict__ cnt, const float* __restrict__ W1,
                      unsigned short* __restrict__ wt_g) {
    int b = blockIdx.x, t = threadIdx.x;
    if (b < ZBLK) {
        int i = (b * 256 + t) * 4;
        if (i < CNTW) *(int4*)(cnt + i) = (int4){0, 0, 0, 0};
    } else {
        int idx = (b - ZBLK) * 256 + t;       // 16384 tasks
        int c = idx >> 8, k = idx & 255;
        wt_g[idx] = f2bf(W1[(size_t)k * HF + c]);
    }
}

// ---- degree histogram + RANK capture: 8 edges/thread, XCD-pinned segments --
__global__ __launch_bounds__(256) void k_hist(const int* __restrict__ dst,
                                              int* __restrict__ cnt,
                                              int* __restrict__ rank) {
    int b   = blockIdx.x;
    int seg = b & (NSEG - 1);
    int grp = b >> 3;
    int e0  = grp * ECHUNK + threadIdx.x;
    int d[8];
    #pragma unroll
    for (int i = 0; i < 8; ++i) {
        int e = e0 + i * 256;
        d[i] = (e < NE) ? dst[e] : -1;    // -1 -> never matches a segment
    }
    #pragma unroll
    for (int i = 0; i < 8; ++i) {
        if ((unsigned)d[i] / (unsigned)SEGW == (unsigned)seg)
            rank[e0 + i * 256] = atomicAdd(&cnt[d[i]], 1);
    }
}

// ---- block-reduce of cnt -> bsum, fused dinv = rsqrt(cnt+1) ----------------
__global__ __launch_bounds__(256) void k_reduce(const int* __restrict__ cnt,
                                                int* __restrict__ bsum,
                                                float* __restrict__ dinv) {
    int t = threadIdx.x;
    int i0 = blockIdx.x * SCAN_CHUNK + t * 4;
    int s = 0;
    float dv[4] = {0.f, 0.f, 0.f, 0.f};
    #pragma unroll
    for (int q = 0; q < 4; ++q) {
        if (i0 + q < NN) {
            int c = cnt[i0 + q];
            s += c;
            dv[q] = rsqrtf((float)(c + 1));
        }
    }
    if (i0 + 3 < NN) *(float4*)(dinv + i0) = (float4){dv[0], dv[1], dv[2], dv[3]};
    else { for (int q = 0; q < 4; ++q) if (i0 + q < NN) dinv[i0 + q] = dv[q]; }
    #pragma unroll
    for (int off = 32; off > 0; off >>= 1) s += __shfl_down(s, off);
    __shared__ int wsum[4];
    int lane = t & 63, wid = t >> 6;
    if (lane == 0) wsum[wid] = s;
    __syncthreads();
    if (t == 0) bsum[blockIdx.x] = wsum[0] + wsum[1] + wsum[2] + wsum[3];
}

// ---- scan: each block derives its own prefix from bsum ---------------------
__global__ __launch_bounds__(256) void k_scan(const int* __restrict__ cnt,
                                              const int* __restrict__ bsum,
                                              int* __restrict__ rowptr) {
    int t = threadIdx.x;
    int b = blockIdx.x;
    int lane = t & 63, wid = t >> 6;

    int p = 0;
    if (lane < b) p += bsum[lane];
    if (64 + lane < b) p += bsum[64 + lane];
    #pragma unroll
    for (int off = 32; off > 0; off >>= 1) p += __shfl_down(p, off);
    int blockBase = __shfl(p, 0);

    int i0 = b * SCAN_CHUNK + t * 4;
    int v0 = 0, v1 = 0, v2 = 0, v3 = 0;
    if (i0 + 0 < NN) v0 = cnt[i0 + 0];
    if (i0 + 1 < NN) v1 = cnt[i0 + 1];
    if (i0 + 2 < NN) v2 = cnt[i0 + 2];
    if (i0 + 3 < NN) v3 = cnt[i0 + 3];
    int tsum = v0 + v1 + v2 + v3;
    int incl = tsum;
    #pragma unroll
    for (int off = 1; off < 64; off <<= 1) {
        int n = __shfl_up(incl, off);
        if (lane >= off) incl += n;
    }
    __shared__ int wsum[4];
    if (lane == 63) wsum[wid] = incl;
    __syncthreads();
    int woff = 0;
    for (int w = 0; w < wid; ++w) woff += wsum[w];
    int excl = woff + (incl - tsum) + blockBase;
    int e0 = excl, e1 = e0 + v0, e2 = e1 + v1, e3 = e2 + v2;
    if (i0 + 0 < NN) rowptr[i0 + 0] = e0;
    if (i0 + 1 < NN) rowptr[i0 + 1] = e1;
    if (i0 + 2 < NN) rowptr[i0 + 2] = e2;
    if (i0 + 3 < NN) rowptr[i0 + 3] = e3;
    if (i0 + 3 == NN - 1) rowptr[NN] = e3 + v3;
}

// ---- FUSED: gemm1 (blocks 0..GB-1) || atomic-free scatter (blocks GB..) ----
// gemm1: x staged per 32-K tile via global_load_lds (fire-and-forget, no VGPR
// cost). XOR-swizzled both sides (linear LDS dest + swizzled SOURCE +
// swizzled READ, same involution gs^(r&7)). m97 pipeline: issue tile s+1,
// compute tile s, barrier. Scatter: zero atomics (rank from hist).
__global__ __launch_bounds__(256, 4) void k_gs(const float* __restrict__ x,
                                               const unsigned short* __restrict__ wt_g,
                                               unsigned short* __restrict__ h1,
                                               const int* __restrict__ src,
                                               const int* __restrict__ dst,
                                               const int* __restrict__ rank,
                                               const int* __restrict__ rowptr,
                                               int* __restrict__ eidx) {
    __shared__ float xs[2][128 * 32];   // 32KB double-buffered x tile
    int b = blockIdx.x;
    int t = threadIdx.x;

    if (b >= GB) {
        // ---- atomic-free scatter path ----
        int sb = b - GB;
        int e0 = sb * ECHUNK + t;
        #pragma unroll
        for (int i = 0; i < 8; ++i) {
            int e = e0 + i * 256;
            if (e < NE) {
                int d = dst[e];
                eidx[rowptr[d] + rank[e]] = src[e];
            }
        }
        return;
    }

    // ---- gemm1 path ----
    int w = t >> 6, l = t & 63;
    int row0 = b * 128;
    int m = l & 15;
    int g = l >> 4;
    const unsigned short* wb0 = wt_g + (size_t)(0 * 16 + m) * 256 + g * 8;
    const unsigned short* wb1 = wt_g + (size_t)(1 * 16 + m) * 256 + g * 8;
    const unsigned short* wb2 = wt_g + (size_t)(2 * 16 + m) * 256 + g * 8;
    const unsigned short* wb3 = wt_g + (size_t)(3 * 16 + m) * 256 + g * 8;

    f32x4 acc[2][4];
    #pragma unroll
    for (int i = 0; i < 2; ++i)
        #pragma unroll
        for (int j = 0; j < 4; ++j) acc[i][j] = (f32x4){0.f, 0.f, 0.f, 0.f};

    auto stage = [&](int s) {
        int kb = s * 32;
        #pragma unroll
        for (int p = 0; p < 4; ++p) {
            int q  = p * 256 + t;
            int r  = q >> 3;
            int gs = q & 7;
            int gr = row0 + r; if (gr > NN - 1) gr = NN - 1;
            const float* srcp = x + (size_t)gr * INF + kb + ((gs ^ (r & 7)) << 2);
            gload_lds16(srcp, &xs[s & 1][q * 4]);
        }
    };

    stage(0);
    __syncthreads();

    int r0 = w * 32 + m;        // row within tile (mt=0)
    int r1 = r0 + 16;           // (mt=1); r1&7 == r0&7
    int x0 = ((2 * g) ^ (r0 & 7)) << 2;         // swizzled slot (floats)
    int x1 = ((2 * g + 1) ^ (r0 & 7)) << 2;

    #pragma unroll
    for (int s = 0; s < 8; ++s) {
        if (s + 1 < 8) stage(s + 1);
        const float* bufp = xs[s & 1];
        float4 c00 = *(const float4*)(bufp + r0 * 32 + x0);
        float4 c01 = *(const float4*)(bufp + r0 * 32 + x1);
        float4 c10 = *(const float4*)(bufp + r1 * 32 + x0);
        float4 c11 = *(const float4*)(bufp + r1 * 32 + x1);
        int kb = s * 32;
        sh8 b0 = *(const sh8*)(wb0 + kb);
        sh8 b1 = *(const sh8*)(wb1 + kb);
        sh8 b2 = *(const sh8*)(wb2 + kb);
        sh8 b3 = *(const sh8*)(wb3 + kb);
        us8 a0u = { f2bf(c00.x), f2bf(c00.y), f2bf(c00.z), f2bf(c00.w),
                    f2bf(c01.x), f2bf(c01.y), f2bf(c01.z), f2bf(c01.w) };
        us8 a1u = { f2bf(c10.x), f2bf(c10.y), f2bf(c10.z), f2bf(c10.w),
                    f2bf(c11.x), f2bf(c11.y), f2bf(c11.z), f2bf(c11.w) };
        sh8 a0 = __builtin_bit_cast(sh8, a0u);
        sh8 a1 = __builtin_bit_cast(sh8, a1u);
        acc[0][0] = __builtin_amdgcn_mfma_f32_16x16x32_bf16(a0, b0, acc[0][0], 0, 0, 0);
        acc[1][0] = __builtin_amdgcn_mfma_f32_16x16x32_bf16(a1, b0, acc[1][0], 0, 0, 0);
        acc[0][1] = __builtin_amdgcn_mfma_f32_16x16x32_bf16(a0, b1, acc[0][1], 0, 0, 0);
        acc[1][1] = __builtin_amdgcn_mfma_f32_16x16x32_bf16(a1, b1, acc[1][1], 0, 0, 0);
        acc[0][2] = __builtin_amdgcn_mfma_f32_16x16x32_bf16(a0, b2, acc[0][2], 0, 0, 0);
        acc[1][2] = __builtin_amdgcn_mfma_f32_16x16x32_bf16(a1, b2, acc[1][2], 0, 0, 0);
        acc[0][3] = __builtin_amdgcn_mfma_f32_16x16x32_bf16(a0, b3, acc[0][3], 0, 0, 0);
        acc[1][3] = __builtin_amdgcn_mfma_f32_16x16x32_bf16(a1, b3, acc[1][3], 0, 0, 0);
        __syncthreads();
    }

    #pragma unroll
    for (int mt = 0; mt < 2; ++mt) {
        #pragma unroll
        for (int r = 0; r < 4; ++r) {
            int gr = row0 + w * 32 + mt * 16 + (l >> 4) * 4 + r;
            if (gr < NN) {
                #pragma unroll
                for (int nt = 0; nt < 4; ++nt)
                    h1[(size_t)gr * HF + nt * 16 + (l & 15)] = f2bf(acc[mt][nt][r]);
            }
        }
    }
}

// ---- Gather layer 1: 8 nodes/wave, 8 lanes/node, lane owns 8 feats ---------
__global__ __launch_bounds__(256) void k_gather1(const int* __restrict__ rowptr,
                                                 const int* __restrict__ eidx,
                                                 const float* __restrict__ dinv,
                                                 const unsigned short* __restrict__ h1,
                                                 const float* __restrict__ b1,
                                                 const float* __restrict__ W2,
                                                 unsigned short* __restrict__ h2) {
    __shared__ float w2L[HF * OF];     // 4KB, [k][j]
    __shared__ float hrL[32][HF + 4];  // 8.5KB, stride 68 (bank-spread)
    int t = threadIdx.x;
    *(float4*)(w2L + t * 4) = *(const float4*)(W2 + t * 4);

    int nodeL = t >> 3;
    int fg    = t & 7;
    int v     = blockIdx.x * 32 + nodeL;   // NN = 3125*32 exact
    int beg = rowptr[v], end = rowptr[v + 1];

    float acc[8] = {};
    int   s_n = 0;  float w_n = 0.f;  us8 h_n = {};
    if (beg < end) {
        s_n = eidx[beg];
        w_n = dinv[s_n];
        h_n = *(const us8*)(h1 + (size_t)s_n * HF + fg * 8);
    }
    for (int i = beg; i < end; ++i) {
        float w_c = w_n;  us8 h_c = h_n;
        if (i + 1 < end) {
            s_n = eidx[i + 1];
            w_n = dinv[s_n];
            h_n = *(const us8*)(h1 + (size_t)s_n * HF + fg * 8);
        }
        #pragma unroll
        for (int q = 0; q < 8; ++q) acc[q] += w_c * bf2f(h_c[q]);
    }

    {
        float dv = dinv[v], sl = dv * dv;
        us8 hv = *(const us8*)(h1 + (size_t)v * HF + fg * 8);
        #pragma unroll
        for (int q = 0; q < 8; ++q) {
            float val = dv * acc[q] + sl * bf2f(hv[q]) + b1[fg * 8 + q];
            hrL[nodeL][fg * 8 + q] = val > 0.f ? val : 0.f;
        }
    }
    __syncthreads();

    #pragma unroll
    for (int T = t; T < 512; T += 256) {
        int n = T >> 4, j = T & 15;
        const float* hr = hrL[n];
        float p = 0.f;
        #pragma unroll
        for (int k = 0; k < HF; ++k) p += hr[k] * w2L[k * OF + j];
        h2[(size_t)(blockIdx.x * 32 + n) * OF + j] = f2bf(p);
    }
}

// ---- Gather layer 2: 16 nodes/block, 16 lanes/node, lane owns 1 out-feat ---
__global__ __launch_bounds__(256) void k_gather2(const int* __restrict__ rowptr,
                                                 const int* __restrict__ eidx,
                                                 const float* __restrict__ dinv,
                                                 const unsigned short* __restrict__ h2,
                                                 const float* __restrict__ b2,
                                                 float* __restrict__ out) {
    int t     = threadIdx.x;
    int nodeL = t >> 4;
    int j     = t & 15;
    int v     = blockIdx.x * 16 + nodeL;   // NN = 6250*16 exact
    int beg = rowptr[v], end = rowptr[v + 1];

    float acc = 0.f;
    int   s_n = 0;  float w_n = 0.f;  unsigned short h_n = 0;
    if (beg < end) {
        s_n = eidx[beg];
        w_n = dinv[s_n];
        h_n = h2[(size_t)s_n * OF + j];
    }
    for (int i = beg; i < end; ++i) {
        float w_c = w_n;  unsigned short h_c = h_n;
        if (i + 1 < end) {
            s_n = eidx[i + 1];
            w_n = dinv[s_n];
            h_n = h2[(size_t)s_n * OF + j];
        }
        acc += w_c * bf2f(h_c);
    }
    float dv = dinv[v];
    out[(size_t)v * OF + j] = dv * acc + dv * dv * bf2f(h2[(size_t)v * OF + j]) + b2[j];
}

extern "C" void kernel_launch(void* const* d_in, const int* in_sizes, int n_in,
                              void* d_out, int out_size, void* d_ws, size_t ws_size,
                              hipStream_t stream) {
    const float* x   = (const float*)d_in[0];
    const int*   ei  = (const int*)d_in[1];
    const int*   src = ei;
    const int*   dst = ei + NE;
    const float* W1  = (const float*)d_in[2];
    const float* b1  = (const float*)d_in[3];
    const float* W2  = (const float*)d_in[4];
    const float* b2  = (const float*)d_in[5];
    float* out = (float*)d_out;

    // workspace layout (4B units)
    float* dinv   = (float*)d_ws;                          // [CNTW]
    unsigned short* h1b = (unsigned short*)(dinv + CNTW);  // [NN*64] bf16
    unsigned short* h2b = (unsigned short*)(h1b + (size_t)NN * HF);  // [NN*16] bf16
    int*   cnt    = (int*)(h2b + (size_t)NN * OF + (size_t)NN * OF); // [CNTW]
    int*   rowptr = cnt + CNTW;                            // [100352]
    int*   rank   = rowptr + 100352;                       // [NE]
    int*   eidx   = rank + NE;                             // [NE]
    int*   bsum   = eidx + NE;                             // [128]
    unsigned short* wt_g = (unsigned short*)(bsum + 128);  // [64*256] bf16

    // CSR build + norms + W pre-transpose
    k_pre<<<ZBLK + 64, 256, 0, stream>>>(cnt, W1, wt_g);
    k_hist<<<SB, 256, 0, stream>>>(dst, cnt, rank);
    k_reduce<<<NBLK, 256, 0, stream>>>(cnt, bsum, dinv);
    k_scan<<<NBLK, 256, 0, stream>>>(cnt, bsum, rowptr);

    // gemm1 || atomic-free scatter in one launch
    k_gs<<<GB + SCB, 256, 0, stream>>>(x, wt_g, h1b, src, dst, rank, rowptr, eidx);

    // layer 1 aggregation (+ fused layer-2 GEMM)
    k_gather1<<<NN / 32, 256, 0, stream>>>(rowptr, eidx, dinv, h1b, b1, W2, h2b);

    // layer 2 aggregation
    k_gather2<<<NN / 16, 256, 0, stream>>>(rowptr, eidx, dinv, h2b, b2, out);
}